// Round 7
// baseline (731.425 us; speedup 1.0000x reference)
//
#include <hip/hip_runtime.h>
#include <hip/hip_cooperative_groups.h>
#include <float.h>

namespace cg = cooperative_groups;

#define N_NODES 50000
#define N_EDGES 600000
#define D 128
#define N_GRAPHS 64
#define NTHR 256
#define NG32 ((N_NODES + 31) / 32)        // 1563 gather node-groups
#define NT64 ((N_NODES + 63) / 64)        // 782 gemm tiles
#define SCAN_NBLK ((N_NODES + 255) / 256) // 196

typedef __attribute__((ext_vector_type(8))) short short8;   // 8 bf16
typedef __attribute__((ext_vector_type(4))) float floatx4;

__device__ inline float bf2f(unsigned short h) {
    return __uint_as_float((unsigned)h << 16);
}
__device__ inline unsigned short f2bf(float f) {
    unsigned u = __float_as_uint(f);
    return (unsigned short)((u + 0x7fffu + ((u >> 16) & 1u)) >> 16);   // RNE
}

// ---- accumulate one i8 row-chunk (16 bytes) with per-row scale ----------------
#define ACCQ(u, ss) {                                                            \
    int w0_ = (u).x, w1_ = (u).y, w2_ = (u).z, w3_ = (u).w;                      \
    a[ 0] += (float)(signed char)(w0_      ) * (ss);                             \
    a[ 1] += (float)(signed char)(w0_ >>  8) * (ss);                             \
    a[ 2] += (float)(signed char)(w0_ >> 16) * (ss);                             \
    a[ 3] += (float)(w0_ >> 24)              * (ss);                             \
    a[ 4] += (float)(signed char)(w1_      ) * (ss);                             \
    a[ 5] += (float)(signed char)(w1_ >>  8) * (ss);                             \
    a[ 6] += (float)(signed char)(w1_ >> 16) * (ss);                             \
    a[ 7] += (float)(w1_ >> 24)              * (ss);                             \
    a[ 8] += (float)(signed char)(w2_      ) * (ss);                             \
    a[ 9] += (float)(signed char)(w2_ >>  8) * (ss);                             \
    a[10] += (float)(signed char)(w2_ >> 16) * (ss);                             \
    a[11] += (float)(w2_ >> 24)              * (ss);                             \
    a[12] += (float)(signed char)(w3_      ) * (ss);                             \
    a[13] += (float)(signed char)(w3_ >>  8) * (ss);                             \
    a[14] += (float)(signed char)(w3_ >> 16) * (ss);                             \
    a[15] += (float)(w3_ >> 24)              * (ss); }

__device__ inline short8 deq8(int2 u, float ss) {
    short8 r;
    r[0] = (short)f2bf((float)(signed char)(u.x      ) * ss);
    r[1] = (short)f2bf((float)(signed char)(u.x >>  8) * ss);
    r[2] = (short)f2bf((float)(signed char)(u.x >> 16) * ss);
    r[3] = (short)f2bf((float)(u.x >> 24)              * ss);
    r[4] = (short)f2bf((float)(signed char)(u.y      ) * ss);
    r[5] = (short)f2bf((float)(signed char)(u.y >>  8) * ss);
    r[6] = (short)f2bf((float)(signed char)(u.y >> 16) * ss);
    r[7] = (short)f2bf((float)(u.y >> 24)              * ss);
    return r;
}

struct Params {
    const float* x; const int* ei; const int* batch;
    const float* Wr0; const float* Wo0; const float* br0;
    const float* Wr1; const float* Wo1; const float* br1;
    const float* Wr2; const float* Wo2; const float* br2;
    const float* W1; const float* b1; const float* W2; const float* b2;
    float* out;
    signed char* xq0; signed char* xq1; signed char* xq2;
    float* xs0; float* xs1; float* xs2;
    unsigned short* aggb;
    unsigned short* Bb0; unsigned short* Bb1; unsigned short* Bb2;
    float* g; int* deg; int* row_start; int* cursor; int* csr_src; int* blockSums;
};

// ---------------- B staging: global -> LDS, MFMA-fragment order ----------------
__device__ inline void stage_b_half(unsigned short* sB, const unsigned short* __restrict__ Bb,
                                    int tid, int h) {
#pragma unroll
    for (int i = 0; i < 8; ++i) {
        int flat = tid + i * 256;            // 0..2047
        int fi = flat >> 6, lnn = flat & 63; // frag idx / lane
        int mm = lnn & 15, qq = lnn >> 4;
        int ksL = fi >> 3, tt = fi & 7;
        short8 v = *(const short8*)(Bb + (size_t)(tt * 16 + mm) * 256
                                    + (h * 4 + ksL) * 32 + qq * 8);
        *(short8*)(sB + (size_t)flat * 8) = v;
    }
}

// ---------------- ONE persistent cooperative kernel ---------------------------
// Phases: cast/prep | count | block_sum | scan_write | fill_csr |
//         3 x (gather -> gemm[/pool]) | head.  grid.sync() between phases.
// Grid size is determined at launch via occupancy query -> co-residency holds
// by construction; every phase loop strides by gridDim.x.

__global__ __launch_bounds__(NTHR, 2) void mega(Params P) {
    cg::grid_group grid = cg::this_grid();
    __shared__ union U {
        unsigned short b[16384];   // 32 KB B-half
        float c[64 * 130];         // 33.3 KB C tile
        int sc[512];               // scan scratch
    } sh;
    __shared__ int bl[64];
    const int tid  = threadIdx.x;
    const int bid  = blockIdx.x;
    const int nblk = gridDim.x;

    // ---- P0: x -> i8 rows + scales, pack Bb, zero deg, init g ----
    {
        const int total = N_NODES * 16 + 3 * 128 * 256 + N_NODES + N_GRAPHS * D;
        for (int t = bid * NTHR + tid; t < total; t += nblk * NTHR) {
            if (t < N_NODES * 16) {
                int node = t >> 4, ln = t & 15;
                const float4* xr = (const float4*)(P.x + (size_t)node * D + ln * 8);
                float4 v0 = xr[0], v1 = xr[1];
                float v[8] = {v0.x, v0.y, v0.z, v0.w, v1.x, v1.y, v1.z, v1.w};
                float am = 0.f;
#pragma unroll
                for (int i = 0; i < 8; ++i) am = fmaxf(am, fabsf(v[i]));
#pragma unroll
                for (int mm = 1; mm < 16; mm <<= 1) am = fmaxf(am, __shfl_xor(am, mm, 16));
                float inv = (am > 0.f) ? 127.f / am : 0.f;
                int q0 = 0, q1 = 0;
#pragma unroll
                for (int i = 0; i < 4; ++i) { int q = (int)rintf(v[i]     * inv); q0 |= (q & 0xff) << (8 * i); }
#pragma unroll
                for (int i = 0; i < 4; ++i) { int q = (int)rintf(v[4 + i] * inv); q1 |= (q & 0xff) << (8 * i); }
                int2 qp; qp.x = q0; qp.y = q1;
                *(int2*)(P.xq0 + (size_t)node * D + ln * 8) = qp;
                if (ln == 0) P.xs0[node] = am * (1.f / 127.f);
            } else {
                int w = t - N_NODES * 16;
                if (w < 3 * 128 * 256) {
                    int l = w >> 15;
                    int r = w & 32767;
                    int o = r >> 8, k = r & 255;
                    const float* Wr = (l == 0) ? P.Wr0 : (l == 1) ? P.Wr1 : P.Wr2;
                    const float* Wo = (l == 0) ? P.Wo0 : (l == 1) ? P.Wo1 : P.Wo2;
                    unsigned short* B = (l == 0) ? P.Bb0 : (l == 1) ? P.Bb1 : P.Bb2;
                    float v = (k < 128) ? Wr[o * 128 + k] : Wo[o * 128 + (k - 128)];
                    B[r] = f2bf(v);
                } else {
                    w -= 3 * 128 * 256;
                    if (w < N_NODES) P.deg[w] = 0;
                    else {
                        w -= N_NODES;
                        if (w < N_GRAPHS * D) P.g[w] = -FLT_MAX;
                    }
                }
            }
        }
    }
    grid.sync();

    // ---- P1: count degrees ----
    for (int e = bid * NTHR + tid; e < N_EDGES; e += nblk * NTHR)
        atomicAdd(&P.deg[P.ei[N_EDGES + e]], 1);
    grid.sync();

    // ---- P2: per-tile sums ----
    for (int vb = bid; vb < SCAN_NBLK; vb += nblk) {
        int i = vb * 256 + tid;
        sh.sc[tid] = (i < N_NODES) ? P.deg[i] : 0;
        __syncthreads();
        for (int off = 128; off > 0; off >>= 1) {
            if (tid < off) sh.sc[tid] += sh.sc[tid + off];
            __syncthreads();
        }
        if (tid == 0) P.blockSums[vb] = sh.sc[0];
        __syncthreads();
    }
    grid.sync();

    // ---- P3: scan + write row_start/cursor ----
    for (int vb = bid; vb < SCAN_NBLK; vb += nblk) {
        int* bs = sh.sc;
        int* s  = sh.sc + 256;
        bs[tid] = (tid < SCAN_NBLK) ? P.blockSums[tid] : 0;
        __syncthreads();
        for (int off = 1; off < 256; off <<= 1) {
            int t2 = (tid >= off) ? bs[tid - off] : 0;
            __syncthreads();
            bs[tid] += t2;
            __syncthreads();
        }
        int myOff = (vb == 0) ? 0 : bs[vb - 1];
        if (vb == 0 && tid == 255) P.row_start[N_NODES] = bs[255];
        int i = vb * 256 + tid;
        int v = (i < N_NODES) ? P.deg[i] : 0;
        s[tid] = v;
        __syncthreads();
        for (int off = 1; off < 256; off <<= 1) {
            int t2 = (tid >= off) ? s[tid - off] : 0;
            __syncthreads();
            s[tid] += t2;
            __syncthreads();
        }
        if (i < N_NODES) {
            int rs = myOff + s[tid] - v;
            P.row_start[i] = rs;
            P.cursor[i]    = rs;
        }
        __syncthreads();
    }
    grid.sync();

    // ---- P4: fill csr ----
    for (int e = bid * NTHR + tid; e < N_EDGES; e += nblk * NTHR) {
        int dst = P.ei[N_EDGES + e];
        int pos = atomicAdd(&P.cursor[dst], 1);
        P.csr_src[pos] = P.ei[e];
    }
    grid.sync();

    const int wave = tid >> 6, lane = tid & 63, m = lane & 15, quad = lane >> 4;
    const int grp = tid >> 3, ln8 = tid & 7;

    for (int L = 0; L < 3; ++L) {
        const signed char* xq = (L == 0) ? P.xq0 : (L == 1) ? P.xq1 : P.xq2;
        const float*       xs = (L == 0) ? P.xs0 : (L == 1) ? P.xs1 : P.xs2;
        const unsigned short* Bb = (L == 0) ? P.Bb0 : (L == 1) ? P.Bb1 : P.Bb2;
        const float* bias = (L == 0) ? P.br0 : (L == 1) ? P.br1 : P.br2;
        signed char* Oq = (L == 0) ? P.xq1 : P.xq2;
        float*       Os = (L == 0) ? P.xs1 : P.xs2;

        // ---- gather: 8 lanes/node, 16 i8/lane, 4 rows in flight ----
        for (int vb = bid; vb < NG32; vb += nblk) {
            int node = vb * 32 + grp;
            if (node < N_NODES) {
                int beg = P.row_start[node];
                int end = P.row_start[node + 1];
                float a[16];
#pragma unroll
                for (int i = 0; i < 16; ++i) a[i] = 0.f;
                for (int base = beg; base < end; base += 8) {
                    int n = end - base; if (n > 8) n = 8;
                    int idx = (ln8 < n) ? P.csr_src[base + ln8] : 0;
                    int j = 0;
                    for (; j + 3 < n; j += 4) {
                        int s0 = __shfl(idx, j,     8); int s1 = __shfl(idx, j + 1, 8);
                        int s2 = __shfl(idx, j + 2, 8); int s3 = __shfl(idx, j + 3, 8);
                        int4 u0 = *(const int4*)(xq + (size_t)s0 * D + ln8 * 16);
                        int4 u1 = *(const int4*)(xq + (size_t)s1 * D + ln8 * 16);
                        int4 u2 = *(const int4*)(xq + (size_t)s2 * D + ln8 * 16);
                        int4 u3 = *(const int4*)(xq + (size_t)s3 * D + ln8 * 16);
                        float ss0 = xs[s0], ss1 = xs[s1], ss2 = xs[s2], ss3 = xs[s3];
                        ACCQ(u0, ss0); ACCQ(u1, ss1); ACCQ(u2, ss2); ACCQ(u3, ss3);
                    }
                    for (; j < n; ++j) {
                        int s0 = __shfl(idx, j, 8);
                        int4 u0 = *(const int4*)(xq + (size_t)s0 * D + ln8 * 16);
                        float ss0 = xs[s0];
                        ACCQ(u0, ss0);
                    }
                }
                short8 r0, r1;
#pragma unroll
                for (int i = 0; i < 8; ++i) { r0[i] = (short)f2bf(a[i]); r1[i] = (short)f2bf(a[8 + i]); }
                *(short8*)(P.aggb + (size_t)node * D + ln8 * 16)     = r0;
                *(short8*)(P.aggb + (size_t)node * D + ln8 * 16 + 8) = r1;
            }
        }
        grid.sync();

        // ---- gemm (+quant out) or gemm+pool ----
        for (int vt = bid; vt < NT64; vt += nblk) {
            int row0 = vt * 64;
            int arow = row0 + wave * 16 + m;
            if (arow > N_NODES - 1) arow = N_NODES - 1;

            short8 afA[4];
#pragma unroll
            for (int ks = 0; ks < 4; ++ks)
                afA[ks] = *(const short8*)(P.aggb + (size_t)arow * 128 + ks * 32 + quad * 8);

            float fsr = xs[arow];
            const signed char* xr = xq + (size_t)arow * 128 + quad * 8;
            short8 afX[4];
            afX[0] = deq8(*(const int2*)(xr),      fsr);
            afX[1] = deq8(*(const int2*)(xr + 32), fsr);
            afX[2] = deq8(*(const int2*)(xr + 64), fsr);
            afX[3] = deq8(*(const int2*)(xr + 96), fsr);

            if (L == 2 && tid < 64) {
                int grow = row0 + tid;
                bl[tid] = (grow < N_NODES) ? P.batch[grow] : -1;
            }

            floatx4 acc[8];
#pragma unroll
            for (int t = 0; t < 8; ++t) acc[t] = (floatx4){0.f, 0.f, 0.f, 0.f};

            stage_b_half(sh.b, Bb, tid, 0);
            __syncthreads();
#pragma unroll
            for (int ksL = 0; ksL < 4; ++ksL)
#pragma unroll
                for (int t = 0; t < 8; ++t) {
                    short8 b = *(const short8*)(sh.b + (size_t)((ksL * 8 + t) * 64 + lane) * 8);
                    acc[t] = __builtin_amdgcn_mfma_f32_16x16x32_bf16(afA[ksL], b, acc[t], 0, 0, 0);
                }
            __syncthreads();
            stage_b_half(sh.b, Bb, tid, 1);
            __syncthreads();
#pragma unroll
            for (int ksL = 0; ksL < 4; ++ksL)
#pragma unroll
                for (int t = 0; t < 8; ++t) {
                    short8 b = *(const short8*)(sh.b + (size_t)((ksL * 8 + t) * 64 + lane) * 8);
                    acc[t] = __builtin_amdgcn_mfma_f32_16x16x32_bf16(afX[ksL], b, acc[t], 0, 0, 0);
                }
            __syncthreads();                 // all sB reads done; reuse as C tile

            if (L < 2) {
#pragma unroll
                for (int t = 0; t < 8; ++t) {
                    int col = t * 16 + m;
                    float bv = bias[col];
#pragma unroll
                    for (int r = 0; r < 4; ++r)
                        sh.c[(wave * 16 + quad * 4 + r) * 130 + col] = fmaxf(acc[t][r] + bv, 0.f);
                }
                __syncthreads();

                int lr  = tid >> 2;
                int seg = tid & 3;
                int grow = row0 + lr;
                const float* cp = &sh.c[lr * 130 + seg * 32];
                float vv[32];
                float am = 0.f;
#pragma unroll
                for (int i = 0; i < 32; ++i) { vv[i] = cp[i]; am = fmaxf(am, fabsf(vv[i])); }
                am = fmaxf(am, __shfl_xor(am, 1));
                am = fmaxf(am, __shfl_xor(am, 2));
                float inv = (am > 0.f) ? 127.f / am : 0.f;

                if (grow < N_NODES) {
                    int qd[8];
#pragma unroll
                    for (int d = 0; d < 8; ++d) {
                        int q = 0;
#pragma unroll
                        for (int i = 0; i < 4; ++i) {
                            int qq = (int)rintf(vv[d * 4 + i] * inv);
                            q |= (qq & 0xff) << (8 * i);
                        }
                        qd[d] = q;
                    }
                    int4 p0; p0.x = qd[0]; p0.y = qd[1]; p0.z = qd[2]; p0.w = qd[3];
                    int4 p1; p1.x = qd[4]; p1.y = qd[5]; p1.z = qd[6]; p1.w = qd[7];
                    *(int4*)(Oq + (size_t)grow * 128 + seg * 32)      = p0;
                    *(int4*)(Oq + (size_t)grow * 128 + seg * 32 + 16) = p1;
                    if (seg == 0) Os[grow] = am * (1.f / 127.f);
                }
                __syncthreads();
            } else {
#pragma unroll
                for (int t = 0; t < 8; ++t) {
                    int col = t * 16 + m;
                    float bv = bias[col];
#pragma unroll
                    for (int r = 0; r < 4; ++r)
                        sh.c[(wave * 16 + quad * 4 + r) * 130 + col] = acc[t][r] + bv;
                }
                __syncthreads();

                int nvalid = min(64, N_NODES - row0);
                int b0 = bl[0], b1 = bl[nvalid - 1];   // batch sorted
                int col  = tid & 127;
                int rbeg = (tid >> 7) * 32;
                for (int gg = b0; gg <= b1; ++gg) {
                    float cur = -FLT_MAX;
#pragma unroll
                    for (int r = 0; r < 32; ++r) {
                        int rr = rbeg + r;
                        float v = (bl[rr] == gg) ? sh.c[rr * 130 + col] : -FLT_MAX;
                        cur = fmaxf(cur, v);
                    }
                    if (cur > -FLT_MAX) {
                        float* ad = &P.g[gg * D + col];
                        if (cur >= 0.f) atomicMax((int*)ad, __float_as_int(cur));
                        else            atomicMin((unsigned int*)ad, __float_as_uint(cur));
                    }
                }
                __syncthreads();
            }
        }
        grid.sync();
    }

    // ---- head: one wave per graph (blocks 0..63) ----
    if (bid < N_GRAPHS && tid < 64) {
        int gi = bid;
        float x0 = P.g[gi * D + tid];
        float x1 = P.g[gi * D + 64 + tid];
        float o = P.b2[0];
#pragma unroll
        for (int j = 0; j < 5; ++j) {
            float p = x0 * P.W1[j * D + tid] + x1 * P.W1[j * D + 64 + tid];
#pragma unroll
            for (int off = 32; off > 0; off >>= 1) p += __shfl_xor(p, off, 64);
            o += fmaxf(p + P.b1[j], 0.f) * P.W2[j];
        }
        if (tid == 0) P.out[gi] = o;
    }
}

extern "C" void kernel_launch(void* const* d_in, const int* in_sizes, int n_in,
                              void* d_out, int out_size, void* d_ws, size_t ws_size,
                              hipStream_t stream) {
    Params P;
    P.x     = (const float*)d_in[0];
    P.ei    = (const int*)d_in[1];
    P.batch = (const int*)d_in[2];
    P.Wr0 = (const float*)d_in[3];  P.br0 = (const float*)d_in[4];  P.Wo0 = (const float*)d_in[5];
    P.Wr1 = (const float*)d_in[6];  P.br1 = (const float*)d_in[7];  P.Wo1 = (const float*)d_in[8];
    P.Wr2 = (const float*)d_in[9];  P.br2 = (const float*)d_in[10]; P.Wo2 = (const float*)d_in[11];
    P.W1 = (const float*)d_in[12]; P.b1 = (const float*)d_in[13];
    P.W2 = (const float*)d_in[14]; P.b2 = (const float*)d_in[15];
    P.out = (float*)d_out;

    char* ws = (char*)d_ws;
    const size_t nodeB8 = (size_t)N_NODES * D;                            // 6.4 MB
    P.xq0 = (signed char*)(ws);
    P.xq1 = (signed char*)(ws + 1 * nodeB8);
    P.xq2 = (signed char*)(ws + 2 * nodeB8);
    char* p = ws + 3 * nodeB8;
    P.aggb = (unsigned short*)p;  p += (size_t)N_NODES * D * sizeof(unsigned short);
    P.xs0 = (float*)p;  p += N_NODES * sizeof(float);
    P.xs1 = (float*)p;  p += N_NODES * sizeof(float);
    P.xs2 = (float*)p;  p += N_NODES * sizeof(float);
    P.Bb0 = (unsigned short*)p;   p += 128 * 256 * sizeof(unsigned short);
    P.Bb1 = (unsigned short*)p;   p += 128 * 256 * sizeof(unsigned short);
    P.Bb2 = (unsigned short*)p;   p += 128 * 256 * sizeof(unsigned short);
    P.g         = (float*)p;      p += N_GRAPHS * D * sizeof(float);
    P.deg       = (int*)p;        p += N_NODES * sizeof(int);
    P.row_start = (int*)p;        p += (N_NODES + 1) * sizeof(int);
    P.cursor    = (int*)p;        p += N_NODES * sizeof(int);
    P.csr_src   = (int*)p;        p += N_EDGES * sizeof(int);
    P.blockSums = (int*)p;        p += SCAN_NBLK * sizeof(int);

    // Grid size derived from measured occupancy of THIS compiled kernel so the
    // cooperative launch is valid by construction. Cached across calls; pure
    // host-side queries (no stream ops) -> graph-capture safe.
    static int nblk = 0;
    if (nblk == 0) {
        int per_cu = 0;
        if (hipOccupancyMaxActiveBlocksPerMultiprocessor(&per_cu, mega, NTHR, 0)
                != hipSuccess || per_cu < 1)
            per_cu = 1;
        int ncu = 0;
        int dev = 0;
        hipGetDevice(&dev);
        if (hipDeviceGetAttribute(&ncu, hipDeviceAttributeMultiprocessorCount, dev)
                != hipSuccess || ncu < 1)
            ncu = 256;
        nblk = per_cu * ncu;
        if (nblk < 64) nblk = 64;
    }

    void* args[] = { &P };
    hipLaunchCooperativeKernel((const void*)mega, dim3(nblk), dim3(NTHR),
                               args, 0, stream);
}

// Round 8
// 331.014 us; speedup vs baseline: 2.2096x; 2.2096x over previous
//
#include <hip/hip_runtime.h>
#include <float.h>

#define N_NODES 50000
#define N_EDGES 600000
#define D 128
#define N_GRAPHS 64
#define SCAN_T 256
#define SCAN_NBLK ((N_NODES + SCAN_T - 1) / SCAN_T)   // 196

typedef __attribute__((ext_vector_type(8))) short short8;   // 8 bf16 = 4 VGPRs
typedef __attribute__((ext_vector_type(4))) float floatx4;

__device__ inline float bf2f(unsigned short h) {
    return __uint_as_float((unsigned)h << 16);
}
__device__ inline unsigned short f2bf(float f) {
    unsigned u = __float_as_uint(f);
    return (unsigned short)((u + 0x7fffu + ((u >> 16) & 1u)) >> 16);   // RNE
}

// ---- accumulate one i8 row-chunk (16 bytes) with per-row scale ----------------
#define ACCQ(u, ss) {                                                            \
    int w0_ = (u).x, w1_ = (u).y, w2_ = (u).z, w3_ = (u).w;                      \
    a[ 0] += (float)(signed char)(w0_      ) * (ss);                             \
    a[ 1] += (float)(signed char)(w0_ >>  8) * (ss);                             \
    a[ 2] += (float)(signed char)(w0_ >> 16) * (ss);                             \
    a[ 3] += (float)(w0_ >> 24)              * (ss);                             \
    a[ 4] += (float)(signed char)(w1_      ) * (ss);                             \
    a[ 5] += (float)(signed char)(w1_ >>  8) * (ss);                             \
    a[ 6] += (float)(signed char)(w1_ >> 16) * (ss);                             \
    a[ 7] += (float)(w1_ >> 24)              * (ss);                             \
    a[ 8] += (float)(signed char)(w2_      ) * (ss);                             \
    a[ 9] += (float)(signed char)(w2_ >>  8) * (ss);                             \
    a[10] += (float)(signed char)(w2_ >> 16) * (ss);                             \
    a[11] += (float)(w2_ >> 24)              * (ss);                             \
    a[12] += (float)(signed char)(w3_      ) * (ss);                             \
    a[13] += (float)(signed char)(w3_ >>  8) * (ss);                             \
    a[14] += (float)(signed char)(w3_ >> 16) * (ss);                             \
    a[15] += (float)(w3_ >> 24)              * (ss); }

__device__ inline short8 deq8(int2 u, float ss) {
    short8 r;
    r[0] = (short)f2bf((float)(signed char)(u.x      ) * ss);
    r[1] = (short)f2bf((float)(signed char)(u.x >>  8) * ss);
    r[2] = (short)f2bf((float)(signed char)(u.x >> 16) * ss);
    r[3] = (short)f2bf((float)(u.x >> 24)              * ss);
    r[4] = (short)f2bf((float)(signed char)(u.y      ) * ss);
    r[5] = (short)f2bf((float)(signed char)(u.y >>  8) * ss);
    r[6] = (short)f2bf((float)(signed char)(u.y >> 16) * ss);
    r[7] = (short)f2bf((float)(u.y >> 24)              * ss);
    return r;
}

// ------- prep: x -> i8(+scale), weights -> Bb, zero deg, init g ----------------
// Bb[o][k] row-major-in-k IS the MFMA B-fragment layout (n fixed, k contiguous).

__global__ __launch_bounds__(256) void cast_prep(
    const float* __restrict__ x,
    signed char* __restrict__ xq, float* __restrict__ xs,
    const float* __restrict__ Wr0, const float* __restrict__ Wo0,
    const float* __restrict__ Wr1, const float* __restrict__ Wo1,
    const float* __restrict__ Wr2, const float* __restrict__ Wo2,
    unsigned short* __restrict__ B0, unsigned short* __restrict__ B1,
    unsigned short* __restrict__ B2,
    int* __restrict__ deg, float* __restrict__ g)
{
    int t = blockIdx.x * 256 + threadIdx.x;
    if (t < N_NODES * 16) {
        int node = t >> 4, ln = t & 15;
        const float4* xr = (const float4*)(x + (size_t)node * D + ln * 8);
        float4 v0 = xr[0], v1 = xr[1];
        float v[8] = {v0.x, v0.y, v0.z, v0.w, v1.x, v1.y, v1.z, v1.w};
        float am = 0.f;
#pragma unroll
        for (int i = 0; i < 8; ++i) am = fmaxf(am, fabsf(v[i]));
#pragma unroll
        for (int m = 1; m < 16; m <<= 1) am = fmaxf(am, __shfl_xor(am, m, 16));
        float inv = (am > 0.f) ? 127.f / am : 0.f;
        int q0 = 0, q1 = 0;
#pragma unroll
        for (int i = 0; i < 4; ++i) { int q = (int)rintf(v[i]     * inv); q0 |= (q & 0xff) << (8 * i); }
#pragma unroll
        for (int i = 0; i < 4; ++i) { int q = (int)rintf(v[4 + i] * inv); q1 |= (q & 0xff) << (8 * i); }
        int2 qp; qp.x = q0; qp.y = q1;
        *(int2*)(xq + (size_t)node * D + ln * 8) = qp;
        if (ln == 0) xs[node] = am * (1.f / 127.f);
        return;
    }
    int w = t - N_NODES * 16;
    if (w < 3 * 128 * 256) {
        int l = w >> 15;
        int r = w & 32767;
        int o = r >> 8, k = r & 255;
        const float* Wr = (l == 0) ? Wr0 : (l == 1) ? Wr1 : Wr2;
        const float* Wo = (l == 0) ? Wo0 : (l == 1) ? Wo1 : Wo2;
        unsigned short* B = (l == 0) ? B0 : (l == 1) ? B1 : B2;
        float v = (k < 128) ? Wr[o * 128 + k] : Wo[o * 128 + (k - 128)];
        B[r] = f2bf(v);
        return;
    }
    w -= 3 * 128 * 256;
    if (w < N_NODES) { deg[w] = 0; return; }
    w -= N_NODES;
    if (w < N_GRAPHS * D) g[w] = -FLT_MAX;
}

// ---------------- CSR build (once per launch) ----------------------------------

__global__ void count_deg(const int* __restrict__ ei, int* __restrict__ deg) {
    int e = blockIdx.x * 256 + threadIdx.x;
    if (e < N_EDGES) atomicAdd(&deg[ei[N_EDGES + e]], 1);
}

__global__ __launch_bounds__(SCAN_T) void block_sum(const int* __restrict__ deg,
                                                    int* __restrict__ blockSums) {
    __shared__ int s[SCAN_T];
    int tid = threadIdx.x;
    int i = blockIdx.x * SCAN_T + tid;
    s[tid] = (i < N_NODES) ? deg[i] : 0;
    __syncthreads();
    for (int off = SCAN_T / 2; off > 0; off >>= 1) {
        if (tid < off) s[tid] += s[tid + off];
        __syncthreads();
    }
    if (tid == 0) blockSums[blockIdx.x] = s[0];
}

__global__ __launch_bounds__(SCAN_T) void scan_write(const int* __restrict__ deg,
                                                     const int* __restrict__ blockSums,
                                                     int* __restrict__ row_start,
                                                     int* __restrict__ cursor) {
    __shared__ int bs[SCAN_T];
    __shared__ int s[SCAN_T];
    int tid = threadIdx.x;
    bs[tid] = (tid < SCAN_NBLK) ? blockSums[tid] : 0;
    __syncthreads();
    for (int off = 1; off < SCAN_T; off <<= 1) {
        int tt = (tid >= off) ? bs[tid - off] : 0;
        __syncthreads();
        bs[tid] += tt;
        __syncthreads();
    }
    int myOff = (blockIdx.x == 0) ? 0 : bs[blockIdx.x - 1];
    if (blockIdx.x == 0 && tid == SCAN_T - 1) row_start[N_NODES] = bs[tid];

    int i = blockIdx.x * SCAN_T + tid;
    int v = (i < N_NODES) ? deg[i] : 0;
    s[tid] = v;
    __syncthreads();
    for (int off = 1; off < SCAN_T; off <<= 1) {
        int tt = (tid >= off) ? s[tid - off] : 0;
        __syncthreads();
        s[tid] += tt;
        __syncthreads();
    }
    if (i < N_NODES) {
        int rs = myOff + s[tid] - v;
        row_start[i] = rs;
        cursor[i]    = rs;
    }
}

__global__ void fill_csr(const int* __restrict__ ei, int* __restrict__ cursor,
                         int* __restrict__ csr_src) {
    int e = blockIdx.x * 256 + threadIdx.x;
    if (e < N_EDGES) {
        int dst = ei[N_EDGES + e];
        int pos = atomicAdd(&cursor[dst], 1);
        csr_src[pos] = ei[e];
    }
}

// ---------------- 16-deep gather: one latency round per (most) nodes -----------
// 8 lanes/node; lane ln owns feats ln*16..+15 (one int4 = whole row with 8 lanes).
// Per round: 2 coalesced idx loads -> 16 row loads + 16 scale loads ALL in
// flight -> accumulate. Tail lanes get clamped index + zero scale (no branches).

__global__ __launch_bounds__(256) void gather_q16(
    const signed char* __restrict__ xq, const float* __restrict__ xs,
    const int* __restrict__ row_start, const int* __restrict__ csr_src,
    unsigned short* __restrict__ aggb)
{
    int grp  = threadIdx.x >> 3;              // 32 nodes per block
    int ln   = threadIdx.x & 7;
    int node = blockIdx.x * 32 + grp;
    if (node >= N_NODES) return;
    int beg = row_start[node];
    int end = row_start[node + 1];

    float a[16];
#pragma unroll
    for (int i = 0; i < 16; ++i) a[i] = 0.f;

    for (int base = beg; base < end; base += 16) {
        int last = end - 1;
        int i0 = base + ln;      if (i0 > last) i0 = last;
        int i1 = base + 8 + ln;  if (i1 > last) i1 = last;
        int idx0 = csr_src[i0];                // coalesced
        int idx1 = csr_src[i1];                // coalesced

        int sidx[16];
#pragma unroll
        for (int j = 0; j < 8; ++j) sidx[j]     = __shfl(idx0, j, 8);
#pragma unroll
        for (int j = 0; j < 8; ++j) sidx[8 + j] = __shfl(idx1, j, 8);

        int4 u[16];
#pragma unroll
        for (int j = 0; j < 16; ++j)           // 16 independent 16B row loads
            u[j] = *(const int4*)(xq + (size_t)sidx[j] * D + ln * 16);
        float ss[16];
#pragma unroll
        for (int j = 0; j < 16; ++j)           // 16 scale loads; 0 past end
            ss[j] = (base + j < end) ? xs[sidx[j]] : 0.f;

#pragma unroll
        for (int j = 0; j < 16; ++j) ACCQ(u[j], ss[j]);
    }

    short8 r0, r1;
#pragma unroll
    for (int i = 0; i < 8; ++i) { r0[i] = (short)f2bf(a[i]); r1[i] = (short)f2bf(a[8 + i]); }
    *(short8*)(aggb + (size_t)node * D + ln * 16)     = r0;
    *(short8*)(aggb + (size_t)node * D + ln * 16 + 8) = r1;
}

// ---------------- B staging: global -> LDS, MFMA-fragment order ----------------

__device__ inline void stage_b_half(unsigned short* sB, const unsigned short* __restrict__ Bb,
                                    int tid, int h) {
#pragma unroll
    for (int i = 0; i < 8; ++i) {
        int flat = tid + i * 256;            // 0..2047
        int fi = flat >> 6, lnn = flat & 63; // frag idx / lane
        int mm = lnn & 15, qq = lnn >> 4;
        int ksL = fi >> 3, tt = fi & 7;
        short8 v = *(const short8*)(Bb + (size_t)(tt * 16 + mm) * 256
                                    + (h * 4 + ksL) * 32 + qq * 8);
        *(short8*)(sB + (size_t)flat * 8) = v;
    }
}

// ---------------- MFMA GEMM: O = [agg|x] @ Bb^T + bias, relu, i8 out -----------

struct GemmShared {
    union {
        unsigned short b[16384];   // 32 KB B-half
        float c[64 * 130];         // 33.3 KB C tile
    };
};

__global__ __launch_bounds__(256) void gemm_mfma(
    const unsigned short* __restrict__ aggb,
    const signed char* __restrict__ xq, const float* __restrict__ xs,
    const unsigned short* __restrict__ Bb, const float* __restrict__ bias,
    signed char* __restrict__ Oq, float* __restrict__ Os)
{
    __shared__ GemmShared sh;
    int tid  = threadIdx.x;
    int wave = tid >> 6;
    int lane = tid & 63;
    int m    = lane & 15;
    int quad = lane >> 4;
    int row0 = blockIdx.x * 64 + wave * 16;

    int arow = row0 + m;
    if (arow > N_NODES - 1) arow = N_NODES - 1;

    short8 afA[4];
#pragma unroll
    for (int ks = 0; ks < 4; ++ks)
        afA[ks] = *(const short8*)(aggb + (size_t)arow * 128 + ks * 32 + quad * 8);

    float fsr = xs[arow];
    const signed char* xr = xq + (size_t)arow * 128 + quad * 8;
    short8 afX[4];
    afX[0] = deq8(*(const int2*)(xr),      fsr);
    afX[1] = deq8(*(const int2*)(xr + 32), fsr);
    afX[2] = deq8(*(const int2*)(xr + 64), fsr);
    afX[3] = deq8(*(const int2*)(xr + 96), fsr);

    floatx4 acc[8];
#pragma unroll
    for (int t = 0; t < 8; ++t) acc[t] = (floatx4){0.f, 0.f, 0.f, 0.f};

    stage_b_half(sh.b, Bb, tid, 0);
    __syncthreads();
#pragma unroll
    for (int ksL = 0; ksL < 4; ++ksL)
#pragma unroll
        for (int t = 0; t < 8; ++t) {
            short8 b = *(const short8*)(sh.b + (size_t)((ksL * 8 + t) * 64 + lane) * 8);
            acc[t] = __builtin_amdgcn_mfma_f32_16x16x32_bf16(afA[ksL], b, acc[t], 0, 0, 0);
        }
    __syncthreads();
    stage_b_half(sh.b, Bb, tid, 1);
    __syncthreads();
#pragma unroll
    for (int ksL = 0; ksL < 4; ++ksL)
#pragma unroll
        for (int t = 0; t < 8; ++t) {
            short8 b = *(const short8*)(sh.b + (size_t)((ksL * 8 + t) * 64 + lane) * 8);
            acc[t] = __builtin_amdgcn_mfma_f32_16x16x32_bf16(afX[ksL], b, acc[t], 0, 0, 0);
        }
    __syncthreads();                         // all sB reads done; reuse as C tile

#pragma unroll
    for (int t = 0; t < 8; ++t) {
        int col = t * 16 + m;
        float bv = bias[col];
#pragma unroll
        for (int r = 0; r < 4; ++r)
            sh.c[(wave * 16 + quad * 4 + r) * 130 + col] = fmaxf(acc[t][r] + bv, 0.f);
    }
    __syncthreads();

    // quant + store: 4 threads/row, 32 contiguous cols each
    int lr  = tid >> 2;
    int seg = tid & 3;
    int grow = blockIdx.x * 64 + lr;
    const float* cp = &sh.c[lr * 130 + seg * 32];
    float vv[32];
    float am = 0.f;
#pragma unroll
    for (int i = 0; i < 32; ++i) { vv[i] = cp[i]; am = fmaxf(am, fabsf(vv[i])); }
    am = fmaxf(am, __shfl_xor(am, 1));
    am = fmaxf(am, __shfl_xor(am, 2));
    float inv = (am > 0.f) ? 127.f / am : 0.f;

    if (grow < N_NODES) {
        int qd[8];
#pragma unroll
        for (int d = 0; d < 8; ++d) {
            int q = 0;
#pragma unroll
            for (int i = 0; i < 4; ++i) {
                int qq = (int)rintf(vv[d * 4 + i] * inv);
                q |= (qq & 0xff) << (8 * i);
            }
            qd[d] = q;
        }
        int4 p0; p0.x = qd[0]; p0.y = qd[1]; p0.z = qd[2]; p0.w = qd[3];
        int4 p1; p1.x = qd[4]; p1.y = qd[5]; p1.z = qd[6]; p1.w = qd[7];
        *(int4*)(Oq + (size_t)grow * 128 + seg * 32)      = p0;
        *(int4*)(Oq + (size_t)grow * 128 + seg * 32 + 16) = p1;
        if (seg == 0) Os[grow] = am * (1.f / 127.f);
    }
}

// ---------------- layer-3 GEMM with fused pooled max ---------------------------

struct PoolShared {
    union {
        unsigned short b[16384];     // 32 KB B-half
        float c[64 * 129];           // 33 KB C tile
    };
};

__global__ __launch_bounds__(256) void gemm_pool(
    const unsigned short* __restrict__ aggb,
    const signed char* __restrict__ xq, const float* __restrict__ xs,
    const unsigned short* __restrict__ Bb, const float* __restrict__ bias,
    const int* __restrict__ batch, float* __restrict__ g)
{
    __shared__ PoolShared sh;
    __shared__ int bl[64];
    int tid  = threadIdx.x;
    int wave = tid >> 6;
    int lane = tid & 63;
    int m    = lane & 15;
    int quad = lane >> 4;
    int row0 = blockIdx.x * 64;

    int arow = row0 + wave * 16 + m;
    if (arow > N_NODES - 1) arow = N_NODES - 1;

    short8 afA[4];
#pragma unroll
    for (int ks = 0; ks < 4; ++ks)
        afA[ks] = *(const short8*)(aggb + (size_t)arow * 128 + ks * 32 + quad * 8);

    float fsr = xs[arow];
    const signed char* xr = xq + (size_t)arow * 128 + quad * 8;
    short8 afX[4];
    afX[0] = deq8(*(const int2*)(xr),      fsr);
    afX[1] = deq8(*(const int2*)(xr + 32), fsr);
    afX[2] = deq8(*(const int2*)(xr + 64), fsr);
    afX[3] = deq8(*(const int2*)(xr + 96), fsr);

    floatx4 acc[8];
#pragma unroll
    for (int t = 0; t < 8; ++t) acc[t] = (floatx4){0.f, 0.f, 0.f, 0.f};

    if (tid < 64) {
        int grow = row0 + tid;
        bl[tid] = (grow < N_NODES) ? batch[grow] : -1;
    }
    stage_b_half(sh.b, Bb, tid, 0);
    __syncthreads();
#pragma unroll
    for (int ksL = 0; ksL < 4; ++ksL)
#pragma unroll
        for (int t = 0; t < 8; ++t) {
            short8 b = *(const short8*)(sh.b + (size_t)((ksL * 8 + t) * 64 + lane) * 8);
            acc[t] = __builtin_amdgcn_mfma_f32_16x16x32_bf16(afA[ksL], b, acc[t], 0, 0, 0);
        }
    __syncthreads();
    stage_b_half(sh.b, Bb, tid, 1);
    __syncthreads();
#pragma unroll
    for (int ksL = 0; ksL < 4; ++ksL)
#pragma unroll
        for (int t = 0; t < 8; ++t) {
            short8 b = *(const short8*)(sh.b + (size_t)((ksL * 8 + t) * 64 + lane) * 8);
            acc[t] = __builtin_amdgcn_mfma_f32_16x16x32_bf16(afX[ksL], b, acc[t], 0, 0, 0);
        }
    __syncthreads();                         // all sB reads done; reuse as C tile

#pragma unroll
    for (int t = 0; t < 8; ++t) {
        int col = t * 16 + m;
        float bv = bias[col];
#pragma unroll
        for (int r = 0; r < 4; ++r)
            sh.c[(wave * 16 + quad * 4 + r) * 129 + col] = acc[t][r] + bv;
    }
    __syncthreads();

    int nvalid = min(64, N_NODES - row0);
    int b0 = bl[0], b1 = bl[nvalid - 1];     // batch sorted; 1-3 graphs per block
    int col  = tid & 127;
    int rbeg = (tid >> 7) * 32;
    for (int gg = b0; gg <= b1; ++gg) {
        float cur = -FLT_MAX;
#pragma unroll
        for (int r = 0; r < 32; ++r) {
            int rr = rbeg + r;
            float v = (bl[rr] == gg) ? sh.c[rr * 129 + col] : -FLT_MAX;
            cur = fmaxf(cur, v);
        }
        if (cur > -FLT_MAX) {
            float* ad = &g[gg * D + col];
            if (cur >= 0.f) atomicMax((int*)ad, __float_as_int(cur));
            else            atomicMin((unsigned int*)ad, __float_as_uint(cur));
        }
    }
}

// ---------------- head: one wave per graph -------------------------------------

__global__ __launch_bounds__(64) void mlp_head(const float* __restrict__ g,
                         const float* __restrict__ W1, const float* __restrict__ b1,
                         const float* __restrict__ W2, const float* __restrict__ b2,
                         float* __restrict__ out) {
    int gi = blockIdx.x;
    int lane = threadIdx.x;
    float x0 = g[gi * D + lane];
    float x1 = g[gi * D + 64 + lane];
    float o = b2[0];
#pragma unroll
    for (int j = 0; j < 5; ++j) {
        float p = x0 * W1[j * D + lane] + x1 * W1[j * D + 64 + lane];
#pragma unroll
        for (int off = 32; off > 0; off >>= 1) p += __shfl_xor(p, off, 64);
        o += fmaxf(p + b1[j], 0.f) * W2[j];
    }
    if (lane == 0) out[gi] = o;
}

extern "C" void kernel_launch(void* const* d_in, const int* in_sizes, int n_in,
                              void* d_out, int out_size, void* d_ws, size_t ws_size,
                              hipStream_t stream) {
    const float* x     = (const float*)d_in[0];
    const int*   ei    = (const int*)d_in[1];
    const int*   batch = (const int*)d_in[2];
    const float* Wrel[3]  = {(const float*)d_in[3], (const float*)d_in[6], (const float*)d_in[9]};
    const float* brel[3]  = {(const float*)d_in[4], (const float*)d_in[7], (const float*)d_in[10]};
    const float* Wroot[3] = {(const float*)d_in[5], (const float*)d_in[8], (const float*)d_in[11]};
    const float* W1 = (const float*)d_in[12];
    const float* b1 = (const float*)d_in[13];
    const float* W2 = (const float*)d_in[14];
    const float* b2 = (const float*)d_in[15];
    float* out = (float*)d_out;

    char* ws = (char*)d_ws;
    const size_t nodeB8 = (size_t)N_NODES * D;                            // 6.4 MB
    signed char* xq  = (signed char*)(ws);
    signed char* h1q = (signed char*)(ws + 1 * nodeB8);
    signed char* h2q = (signed char*)(ws + 2 * nodeB8);
    char* p = ws + 3 * nodeB8;
    unsigned short* aggb = (unsigned short*)p;  p += (size_t)N_NODES * D * sizeof(unsigned short);
    float* xs  = (float*)p;  p += N_NODES * sizeof(float);
    float* h1s = (float*)p;  p += N_NODES * sizeof(float);
    float* h2s = (float*)p;  p += N_NODES * sizeof(float);
    unsigned short* Bb0 = (unsigned short*)p;   p += 128 * 256 * sizeof(unsigned short);
    unsigned short* Bb1 = (unsigned short*)p;   p += 128 * 256 * sizeof(unsigned short);
    unsigned short* Bb2 = (unsigned short*)p;   p += 128 * 256 * sizeof(unsigned short);
    float* g        = (float*)p;                p += N_GRAPHS * D * sizeof(float);
    int*   deg      = (int*)p;                  p += N_NODES * sizeof(int);
    int*   row_start= (int*)p;                  p += (N_NODES + 1) * sizeof(int);
    int*   cursor   = (int*)p;                  p += N_NODES * sizeof(int);
    int*   csr_src  = (int*)p;                  p += N_EDGES * sizeof(int);
    int*   blockSums= (int*)p;                  p += SCAN_NBLK * sizeof(int);

    // prep: i8 cast + weight packs + zero deg + init g
    const int cast_total = N_NODES * 16 + 3 * 128 * 256 + N_NODES + N_GRAPHS * D;
    cast_prep<<<(cast_total + 255) / 256, 256, 0, stream>>>(
        x, xq, xs,
        Wrel[0], Wroot[0], Wrel[1], Wroot[1], Wrel[2], Wroot[2],
        Bb0, Bb1, Bb2, deg, g);

    // CSR build (once per call)
    count_deg<<<(N_EDGES + 255) / 256, 256, 0, stream>>>(ei, deg);
    block_sum<<<SCAN_NBLK, SCAN_T, 0, stream>>>(deg, blockSums);
    scan_write<<<SCAN_NBLK, SCAN_T, 0, stream>>>(deg, blockSums, row_start, cursor);
    fill_csr<<<(N_EDGES + 255) / 256, 256, 0, stream>>>(ei, cursor, csr_src);

    const int ggrid = (N_NODES + 31) / 32;                // 1563
    const int mgrid = (N_NODES + 63) / 64;                // 782

    // layer 1
    gather_q16<<<ggrid, 256, 0, stream>>>(xq, xs, row_start, csr_src, aggb);
    gemm_mfma<<<mgrid, 256, 0, stream>>>(aggb, xq, xs, Bb0, brel[0], h1q, h1s);
    // layer 2
    gather_q16<<<ggrid, 256, 0, stream>>>(h1q, h1s, row_start, csr_src, aggb);
    gemm_mfma<<<mgrid, 256, 0, stream>>>(aggb, h1q, h1s, Bb1, brel[1], h2q, h2s);
    // layer 3 + pool
    gather_q16<<<ggrid, 256, 0, stream>>>(h2q, h2s, row_start, csr_src, aggb);
    gemm_pool<<<mgrid, 256, 0, stream>>>(aggb, h2q, h2s, Bb2, brel[2], batch, g);

    mlp_head<<<N_GRAPHS, 64, 0, stream>>>(g, W1, b1, W2, b2, out);
}